// Round 5
// baseline (2397.884 us; speedup 1.0000x reference)
//
#include <hip/hip_runtime.h>
#include <hip/hip_bf16.h>
#include <cstdint>
#include <cstddef>

typedef __bf16 bf16x8 __attribute__((ext_vector_type(8)));
typedef __bf16 bf16x4 __attribute__((ext_vector_type(4)));
typedef __bf16 bf16x2 __attribute__((ext_vector_type(2)));
typedef float  f32x4  __attribute__((ext_vector_type(4)));
typedef float  f32x2  __attribute__((ext_vector_type(2)));

#define T_SEQ 2048
#define CDIM  2048
#define NH    16
#define NG    4
#define DH    128

__device__ __forceinline__ void gl_lds16(const __bf16* g, __bf16* l) {
  __builtin_amdgcn_global_load_lds(
      (const __attribute__((address_space(1))) void*)g,
      (__attribute__((address_space(3))) void*)l, 16, 0, 0);
}

// ---------------- cast f32 -> bf16 (contiguous) ----------------
__global__ __launch_bounds__(256) void cast_bf16_kernel(const float* __restrict__ in,
                                                        __bf16* __restrict__ out) {
  size_t i = ((size_t)blockIdx.x * 256 + threadIdx.x) * 8;
  f32x4 a = *(const f32x4*)(in + i);
  f32x4 b = *(const f32x4*)(in + i + 4);
  bf16x8 o;
#pragma unroll
  for (int j = 0; j < 4; ++j) { o[j] = (__bf16)a[j]; o[4 + j] = (__bf16)b[j]; }
  *(bf16x8*)(out + i) = o;
}

// ---------------- transpose + cast: W[K][N] f32 -> Wt[N][K] bf16 ----------------
__global__ __launch_bounds__(256) void transpose_cast_kernel(const float* __restrict__ W,
                                                             __bf16* __restrict__ Wt,
                                                             int K, int N) {
  __shared__ __bf16 tile[64][68];
  int k0 = blockIdx.x * 64, n0 = blockIdx.y * 64;
  int tid = threadIdx.x;
  int c4 = (tid & 15) * 4, r = tid >> 4;
#pragma unroll
  for (int rr = 0; rr < 4; ++rr) {
    int row = r + rr * 16;
    f32x4 v = *(const f32x4*)(W + (size_t)(k0 + row) * N + n0 + c4);
#pragma unroll
    for (int j = 0; j < 4; ++j) tile[row][c4 + j] = (__bf16)v[j];
  }
  __syncthreads();
  int n = tid >> 2, seg = tid & 3;
  __bf16 vals[16];
#pragma unroll
  for (int j = 0; j < 16; ++j) vals[j] = tile[seg * 16 + j][n];
  __bf16* dst = Wt + (size_t)(n0 + n) * K + k0 + seg * 16;
  *(bf16x8*)(dst)     = *(bf16x8*)(&vals[0]);
  *(bf16x8*)(dst + 8) = *(bf16x8*)(&vals[8]);
}

// ---------------- RoPE + scatter q,k (idempotent internal repeat for profiling) ----------------
__global__ __launch_bounds__(256) void rope_scatter_kernel(const float* __restrict__ qkv,
    const float* __restrict__ cosb, const float* __restrict__ sinb,
    __bf16* __restrict__ qb, __bf16* __restrict__ kb, int rep) {
  int t = blockIdx.x;
  int w = threadIdx.x >> 6, l = threadIdx.x & 63;
  for (int rp = 0; rp < rep; ++rp) {
    asm volatile("" ::: "memory");   // keep each repeat live (no CSE/DSE across reps)
    float c = cosb[t * 64 + l], s = sinb[t * 64 + l];
#pragma unroll
    for (int it = 0; it < 5; ++it) {
      int slot = w + it * 4;
      int g = slot / 5, j = slot % 5;
      const float* src = qkv + (size_t)t * 3072 + g * 768 + j * 128;
      f32x2 xv = *(const f32x2*)(src + 2 * l);
      bf16x2 o;
      o[0] = (__bf16)(xv[0] * c - xv[1] * s);
      o[1] = (__bf16)(xv[0] * s + xv[1] * c);
      __bf16* dst = (j < 4) ? (qb + ((size_t)(g * 4 + j) * T_SEQ + t) * DH)
                            : (kb + ((size_t)g * T_SEQ + t) * DH);
      *(bf16x2*)(dst + 2 * l) = o;
    }
  }
}

// ---------------- v transpose: qkv v-section [t][d] f32 -> vtb[g][d][t] bf16 ----------------
__global__ __launch_bounds__(256) void v_transpose_kernel(const float* __restrict__ qkv,
                                                          __bf16* __restrict__ vtb) {
  __shared__ float vt[64][129];
  int g = blockIdx.x, t0 = blockIdx.y * 64;
  int tid = threadIdx.x;
#pragma unroll
  for (int it = 0; it < 8; ++it) {
    int q = it * 256 + tid;
    int tt = q >> 5, dq = q & 31;
    f32x4 v = *(const f32x4*)(qkv + (size_t)(t0 + tt) * 3072 + g * 768 + 640 + dq * 4);
#pragma unroll
    for (int j = 0; j < 4; ++j) vt[tt][dq * 4 + j] = v[j];
  }
  __syncthreads();
  int d = tid >> 1, half = tid & 1;
  __bf16 outv[32];
#pragma unroll
  for (int j = 0; j < 32; ++j) outv[j] = (__bf16)vt[half * 32 + j][d];
  __bf16* dst = vtb + ((size_t)g * DH + d) * T_SEQ + t0 + half * 32;
#pragma unroll
  for (int q4 = 0; q4 < 4; ++q4) *(bf16x8*)(dst + q4 * 8) = *(bf16x8*)(&outv[q4 * 8]);
}

// ---------------- GEMM: 64x128 tile, BK=64, global_load_lds + T2 XOR swizzle ----------------
// Idempotent internal repeat (acc reset each rep) for per-kernel profiling.
template<int MODE>
__global__ __launch_bounds__(256) void gemm_gl_kernel(
    const __bf16* __restrict__ A, const __bf16* __restrict__ Bt,
    float* __restrict__ Cf, __bf16* __restrict__ Cg, int M, int N, int K, int rep) {
  __shared__ __bf16 Asb[64 * 64];
  __shared__ __bf16 Bsb[128 * 64];
  int m0 = blockIdx.x * 64, n0 = blockIdx.y * 128;
  int tid = threadIdx.x;
  int w = tid >> 6, l = tid & 63;
  int wr = w >> 1, wc = w & 1;
  int lr = l & 15, lg = l >> 4;
  int nk = K >> 6;
  const __bf16* Ab = A + (size_t)m0 * K;
  const __bf16* Bb = Bt + (size_t)n0 * K;
  f32x4 acc[2][4];
  for (int rp = 0; rp < rep; ++rp) {
    asm volatile("" ::: "memory");
#pragma unroll
    for (int i = 0; i < 2; ++i)
#pragma unroll
      for (int j = 0; j < 4; ++j) acc[i][j] = f32x4{0.f, 0.f, 0.f, 0.f};
    for (int kt = 0; kt < nk; ++kt) {
      int k0 = kt << 6;
#pragma unroll
      for (int c = 0; c < 2; ++c) {
        int ca = c * 256 + tid;
        int row = ca >> 3, kseg = ca & 7;
        gl_lds16(Ab + (size_t)row * K + k0 + ((kseg ^ (row & 7)) << 3), Asb + ca * 8);
      }
#pragma unroll
      for (int c = 0; c < 4; ++c) {
        int cb = c * 256 + tid;
        int row = cb >> 3, kseg = cb & 7;
        gl_lds16(Bb + (size_t)row * K + k0 + ((kseg ^ (row & 7)) << 3), Bsb + cb * 8);
      }
      __syncthreads();
      bf16x8 av[2][2], bv[4][2];
#pragma unroll
      for (int i = 0; i < 2; ++i)
#pragma unroll
        for (int kk = 0; kk < 2; ++kk) {
          int row = wr * 32 + i * 16 + lr;
          av[i][kk] = *(const bf16x8*)((const char*)Asb +
              ((row * 128 + kk * 64 + lg * 16) ^ ((lr & 7) << 4)));
        }
#pragma unroll
      for (int j = 0; j < 4; ++j)
#pragma unroll
        for (int kk = 0; kk < 2; ++kk) {
          int row = wc * 64 + j * 16 + lr;
          bv[j][kk] = *(const bf16x8*)((const char*)Bsb +
              ((row * 128 + kk * 64 + lg * 16) ^ ((lr & 7) << 4)));
        }
#pragma unroll
      for (int kk = 0; kk < 2; ++kk)
#pragma unroll
        for (int i = 0; i < 2; ++i)
#pragma unroll
          for (int j = 0; j < 4; ++j)
            acc[i][j] = __builtin_amdgcn_mfma_f32_16x16x32_bf16(av[i][kk], bv[j][kk],
                                                                acc[i][j], 0, 0, 0);
      __syncthreads();
    }
  }
#pragma unroll
  for (int i = 0; i < 2; ++i) {
    int row = m0 + wr * 32 + i * 16 + lg * 4;
#pragma unroll
    for (int j = 0; j < 4; ++j) {
      int col = n0 + wc * 64 + j * 16 + lr;
#pragma unroll
      for (int r = 0; r < 4; ++r) {
        float z = acc[i][j][r];
        if (MODE == 0) {
          Cf[(size_t)(row + r) * N + col] = z;
        } else {
          if (n0 < 3072) {
            Cf[(size_t)(row + r) * 3072 + col] = z;
          } else {
            float sv = z / (1.0f + expf(-z));
            Cg[(size_t)(row + r) * 2048 + (col - 3072)] = (__bf16)sv;
          }
        }
      }
    }
  }
}

// ---------------- retention attention (idempotent internal repeat) ----------------
__global__ __launch_bounds__(256) void attn_kernel(const __bf16* __restrict__ qb,
    const __bf16* __restrict__ kb, const __bf16* __restrict__ vtb, float* __restrict__ y,
    int rep) {
  __shared__ __bf16 kl[64 * 128];
  __shared__ __bf16 vl[128 * 64];
  __shared__ __bf16 pl[4][16 * 64];
  int h = blockIdx.x >> 5, qt = blockIdx.x & 31;
  int g = h >> 2;
  int w = threadIdx.x >> 6, l = threadIdx.x & 63;
  int lr = l & 15, lg = l >> 4;
  int t0b = qt * 64;
  int t0 = t0b + w * 16;
  bf16x8 qf[4];
#pragma unroll
  for (int kbk = 0; kbk < 4; ++kbk)
    qf[kbk] = *(const bf16x8*)(qb + ((size_t)h * T_SEQ + t0 + lr) * DH + kbk * 32 + lg * 8);
  float gamma = 1.0f - exp2f(-5.0f - (float)h);
  float l2g = log2f(gamma);
  const float scale = 0.088388347648318447f;  // 1/sqrt(128)
  f32x4 acc[8];
  for (int rp = 0; rp < rep; ++rp) {
    asm volatile("" ::: "memory");
#pragma unroll
    for (int dc = 0; dc < 8; ++dc) acc[dc] = f32x4{0.f, 0.f, 0.f, 0.f};
    for (int st = 0; st <= qt; ++st) {
      int s0 = st * 64;
      float mind = (float)(t0b - (s0 + 63));
      if (mind > 0.0f && mind * l2g < -25.0f) continue;   // block-uniform skip
#pragma unroll
      for (int it = 0; it < 4; ++it) {
        int fg = it * 256 + threadIdx.x;
        {
          int ss = fg >> 4, gr = fg & 15;
          bf16x8 kv = *(const bf16x8*)(kb + ((size_t)g * T_SEQ + s0 + ss) * DH + gr * 8);
          *(bf16x8*)((char*)kl + ss * 256 + ((gr * 16) ^ ((ss & 7) << 4))) = kv;
        }
        {
          int d = fg >> 3, gv = fg & 7;
          bf16x8 vv = *(const bf16x8*)(vtb + ((size_t)g * DH + d) * T_SEQ + s0 + gv * 8);
          *(bf16x8*)((char*)vl + d * 128 + ((gv * 16) ^ ((d & 7) << 4))) = vv;
        }
      }
      __syncthreads();
#pragma unroll
      for (int sc = 0; sc < 4; ++sc) {
        f32x4 p = {0.f, 0.f, 0.f, 0.f};
        int srow = sc * 16 + lr;
#pragma unroll
        for (int kbk = 0; kbk < 4; ++kbk) {
          bf16x8 kf = *(const bf16x8*)((char*)kl + srow * 256 +
                                       ((kbk * 64 + lg * 16) ^ ((srow & 7) << 4)));
          p = __builtin_amdgcn_mfma_f32_16x16x32_bf16(qf[kbk], kf, p, 0, 0, 0);
        }
#pragma unroll
        for (int r = 0; r < 4; ++r) {
          int tl = lg * 4 + r;
          int diff = (t0 + tl) - (s0 + srow);
          float val = 0.0f;
          if (diff >= 0) val = p[r] * scale * exp2f((float)diff * l2g);
          *(__bf16*)((char*)(pl[w]) + tl * 128 +
                     (((sc * 16 + lr) * 2) ^ ((tl & 7) << 4))) = (__bf16)val;
        }
      }
      bf16x8 pa[2];
#pragma unroll
      for (int kc = 0; kc < 2; ++kc)
        pa[kc] = *(const bf16x8*)((char*)(pl[w]) + lr * 128 +
                                  ((kc * 64 + lg * 16) ^ ((lr & 7) << 4)));
#pragma unroll
      for (int dc = 0; dc < 8; ++dc) {
#pragma unroll
        for (int kc = 0; kc < 2; ++kc) {
          int vrow = dc * 16 + lr;
          bf16x8 vf = *(const bf16x8*)((char*)vl + vrow * 128 +
                                       ((kc * 64 + lg * 16) ^ ((vrow & 7) << 4)));
          acc[dc] = __builtin_amdgcn_mfma_f32_16x16x32_bf16(pa[kc], vf, acc[dc], 0, 0, 0);
        }
      }
      __syncthreads();
    }
  }
#pragma unroll
  for (int dc = 0; dc < 8; ++dc)
#pragma unroll
    for (int r = 0; r < 4; ++r)
      y[((size_t)h * T_SEQ + t0 + lg * 4 + r) * DH + dc * 16 + lr] = acc[dc][r];
}

// ---------------- RMS norm over D per (h,t) + gate multiply -> bf16 [T][C] ----------------
__global__ __launch_bounds__(256) void rms_gate_kernel(const float* __restrict__ y,
                                                       const __bf16* __restrict__ gateb,
                                                       __bf16* __restrict__ ynormb) {
  int f = blockIdx.x * 4 + (threadIdx.x >> 6);   // row = h*2048 + t
  int l = threadIdx.x & 63;
  int h = f >> 11, t = f & 2047;
  const float* row = y + (size_t)f * DH;
  f32x2 v = *(const f32x2*)(row + 2 * l);
  float ss = v[0] * v[0] + v[1] * v[1];
#pragma unroll
  for (int o = 32; o > 0; o >>= 1) ss += __shfl_xor(ss, o, 64);
  float r = rsqrtf(ss * (1.0f / 128.0f) + 1e-5f);
  size_t base = (size_t)t * CDIM + h * DH + 2 * l;
  bf16x2 gv = *(const bf16x2*)(gateb + base);
  bf16x2 o;
  o[0] = (__bf16)(v[0] * r * (float)gv[0]);
  o[1] = (__bf16)(v[1] * r * (float)gv[1]);
  *(bf16x2*)(ynormb + base) = o;
}

extern "C" void kernel_launch(void* const* d_in, const int* in_sizes, int n_in,
                              void* d_out, int out_size, void* d_ws, size_t ws_size,
                              hipStream_t stream) {
  const float* x    = (const float*)d_in[0];
  const float* cosb = (const float*)d_in[1];
  const float* sinb = (const float*)d_in[2];
  // d_in[3] = mask (268MB) -- computed analytically, never read
  const float* Wr   = (const float*)d_in[4];
  const float* Wg   = (const float*)d_in[5];
  const float* Wp   = (const float*)d_in[6];

  char* ws = (char*)d_ws;
  size_t off = 0;
  auto alloc = [&](size_t bytes) { void* p = ws + off; off += (bytes + 255) & ~(size_t)255; return p; };
  __bf16* xb     = (__bf16*)alloc((size_t)CDIM * CDIM * 2);          // 8MB
  __bf16* wtb    = (__bf16*)alloc((size_t)5120 * CDIM * 2);          // 20MB (W_reten^T | W_gate^T)
  __bf16* wpb    = (__bf16*)alloc((size_t)CDIM * CDIM * 2);          // 8MB
  char*   qkvblk = (char*)  alloc((size_t)T_SEQ * 3072 * 4);         // 24MB (reused by y+ynorm)
  __bf16* qb     = (__bf16*)alloc((size_t)NH * T_SEQ * DH * 2);      // 8MB
  __bf16* kbp    = (__bf16*)alloc((size_t)NG * T_SEQ * DH * 2);      // 2MB
  __bf16* vtb    = (__bf16*)alloc((size_t)NG * DH * T_SEQ * 2);      // 2MB
  __bf16* gateb  = (__bf16*)alloc((size_t)CDIM * CDIM * 2);          // 8MB
  float*  qkv    = (float*)qkvblk;
  float*  yb     = (float*)qkvblk;                                    // alias (qkv dead by then)
  __bf16* ynormb = (__bf16*)(qkvblk + (size_t)16 * 1024 * 1024);      // alias tail of qkv block

  // PROFILING ROUND: internal idempotent repeats push suspect kernels above the
  // ~160us harness fills so they surface in rocprof top-5 WITH counters.
  const int REP_GEMM1 = 8, REP_GEMM3 = 24, REP_ATTN = 16, REP_ROPE = 64;

  cast_bf16_kernel<<<2048, 256, 0, stream>>>(x, xb);
  transpose_cast_kernel<<<dim3(32, 48), 256, 0, stream>>>(Wr, wtb, 2048, 3072);
  transpose_cast_kernel<<<dim3(32, 32), 256, 0, stream>>>(Wg, wtb + (size_t)3072 * CDIM, 2048, 2048);
  transpose_cast_kernel<<<dim3(32, 32), 256, 0, stream>>>(Wp, wpb, 2048, 2048);
  gemm_gl_kernel<1><<<dim3(32, 40), 256, 0, stream>>>(xb, wtb, qkv, gateb, 2048, 5120, 2048,
                                                      REP_GEMM1);
  rope_scatter_kernel<<<2048, 256, 0, stream>>>(qkv, cosb, sinb, qb, kbp, REP_ROPE);
  v_transpose_kernel<<<dim3(4, 32), 256, 0, stream>>>(qkv, vtb);
  attn_kernel<<<NH * 32, 256, 0, stream>>>(qb, kbp, vtb, yb, REP_ATTN);
  rms_gate_kernel<<<NH * T_SEQ / 4, 256, 0, stream>>>(yb, gateb, ynormb);
  gemm_gl_kernel<0><<<dim3(32, 16), 256, 0, stream>>>(ynormb, wpb, (float*)d_out, nullptr,
                                                      2048, 2048, 2048, REP_GEMM3);
}

// Round 6
// 181.584 us; speedup vs baseline: 13.2054x; 13.2054x over previous
//
#include <hip/hip_runtime.h>
#include <hip/hip_bf16.h>
#include <cstdint>
#include <cstddef>

typedef __bf16 bf16x8 __attribute__((ext_vector_type(8)));
typedef __bf16 bf16x4 __attribute__((ext_vector_type(4)));
typedef __bf16 bf16x2 __attribute__((ext_vector_type(2)));
typedef float  f32x4  __attribute__((ext_vector_type(4)));
typedef float  f32x2  __attribute__((ext_vector_type(2)));

#define T_SEQ 2048
#define CDIM  2048
#define NH    16
#define NG    4
#define DH    128
#define NCHUNK 32   // T / 64

__device__ __forceinline__ void gl_lds16(const __bf16* g, __bf16* l) {
  __builtin_amdgcn_global_load_lds(
      (const __attribute__((address_space(1))) void*)g,
      (__attribute__((address_space(3))) void*)l, 16, 0, 0);
}

// ---------------- fused preprocess: cast x->bf16, transpose+cast 3 weights ----------------
__global__ __launch_bounds__(256) void pre_kernel(
    const float* __restrict__ x, const float* __restrict__ Wr,
    const float* __restrict__ Wg, const float* __restrict__ Wp,
    __bf16* __restrict__ xb, __bf16* __restrict__ wtb, __bf16* __restrict__ wpb) {
  __shared__ __bf16 tile[64][68];
  int bid = blockIdx.x;
  int tid = threadIdx.x;
  if (bid < 2048) {   // cast x (4M elements)
    size_t i = ((size_t)bid * 256 + tid) * 8;
    f32x4 a = *(const f32x4*)(x + i);
    f32x4 b = *(const f32x4*)(x + i + 4);
    bf16x8 o;
#pragma unroll
    for (int j = 0; j < 4; ++j) { o[j] = (__bf16)a[j]; o[4 + j] = (__bf16)b[j]; }
    *(bf16x8*)(xb + i) = o;
    return;
  }
  int rel = bid - 2048;
  const float* W; __bf16* Wt; int N;
  if (rel < 1536)      { W = Wr; Wt = wtb;                        N = 3072; }
  else if (rel < 2560) { W = Wg; Wt = wtb + (size_t)3072 * CDIM;  N = 2048; rel -= 1536; }
  else                 { W = Wp; Wt = wpb;                        N = 2048; rel -= 2560; }
  const int K = 2048;
  int k0 = (rel & 31) * 64, n0 = (rel >> 5) * 64;
  int c4 = (tid & 15) * 4, r = tid >> 4;
#pragma unroll
  for (int rr = 0; rr < 4; ++rr) {
    int row = r + rr * 16;
    f32x4 v = *(const f32x4*)(W + (size_t)(k0 + row) * N + n0 + c4);
#pragma unroll
    for (int j = 0; j < 4; ++j) tile[row][c4 + j] = (__bf16)v[j];
  }
  __syncthreads();
  int n = tid >> 2, seg = tid & 3;
  __bf16 vals[16];
#pragma unroll
  for (int j = 0; j < 16; ++j) vals[j] = tile[seg * 16 + j][n];
  __bf16* dst = Wt + (size_t)(n0 + n) * K + k0 + seg * 16;
  *(bf16x8*)(dst)     = *(bf16x8*)(&vals[0]);
  *(bf16x8*)(dst + 8) = *(bf16x8*)(&vals[8]);
}

// ---------------- fused: RoPE q,k scatter (blocks 0..2047) + v transpose (blocks 2048..2175) --
__global__ __launch_bounds__(256) void ropevt_kernel(const float* __restrict__ qkv,
    const float* __restrict__ cosb, const float* __restrict__ sinb,
    __bf16* __restrict__ qb, __bf16* __restrict__ kb, __bf16* __restrict__ vtb) {
  __shared__ __bf16 vt[64][136];
  int bid = blockIdx.x;
  int tid = threadIdx.x;
  if (bid < 2048) {     // RoPE
    int t = bid;
    int w = tid >> 6, l = tid & 63;
    float c = cosb[t * 64 + l], s = sinb[t * 64 + l];
#pragma unroll
    for (int it = 0; it < 5; ++it) {
      int slot = w + it * 4;
      int g = slot / 5, j = slot % 5;
      const float* src = qkv + (size_t)t * 3072 + g * 768 + j * 128;
      f32x2 xv = *(const f32x2*)(src + 2 * l);
      bf16x2 o;
      o[0] = (__bf16)(xv[0] * c - xv[1] * s);
      o[1] = (__bf16)(xv[0] * s + xv[1] * c);
      __bf16* dst = (j < 4) ? (qb + ((size_t)(g * 4 + j) * T_SEQ + t) * DH)
                            : (kb + ((size_t)g * T_SEQ + t) * DH);
      *(bf16x2*)(dst + 2 * l) = o;
    }
    return;
  }
  // v transpose: qkv v-section [t][d] f32 -> vtb[g][d][t] bf16
  int rel = bid - 2048;
  int g = rel >> 5, t0 = (rel & 31) * 64;
#pragma unroll
  for (int it = 0; it < 8; ++it) {
    int q = it * 256 + tid;
    int tt = q >> 5, dq = q & 31;
    f32x4 v = *(const f32x4*)(qkv + (size_t)(t0 + tt) * 3072 + g * 768 + 640 + dq * 4);
#pragma unroll
    for (int j = 0; j < 4; ++j) vt[tt][dq * 4 + j] = (__bf16)v[j];
  }
  __syncthreads();
  int d = tid >> 1, half = tid & 1;
  __bf16 outv[32];
#pragma unroll
  for (int j = 0; j < 32; ++j) outv[j] = vt[half * 32 + j][d];
  __bf16* dst = vtb + ((size_t)g * DH + d) * T_SEQ + t0 + half * 32;
#pragma unroll
  for (int q4 = 0; q4 < 4; ++q4) *(bf16x8*)(dst + q4 * 8) = *(bf16x8*)(&outv[q4 * 8]);
}

// ---------------- k transpose: kb[g][t][d] bf16 -> ktb[g][d][t] bf16 ----------------
__global__ __launch_bounds__(256) void kt_kernel(const __bf16* __restrict__ kb,
                                                 __bf16* __restrict__ ktb) {
  __shared__ __bf16 tile[64][136];
  int g = blockIdx.x >> 5, t0 = (blockIdx.x & 31) * 64;
  int tid = threadIdx.x;
#pragma unroll
  for (int it = 0; it < 4; ++it) {
    int fg = it * 256 + tid;
    int tt = fg >> 4, gr = fg & 15;
    bf16x8 v = *(const bf16x8*)(kb + ((size_t)g * T_SEQ + t0 + tt) * DH + gr * 8);
    *(bf16x8*)(&tile[tt][gr * 8]) = v;
  }
  __syncthreads();
  int d = tid >> 1, half = tid & 1;
  __bf16 outv[32];
#pragma unroll
  for (int j = 0; j < 32; ++j) outv[j] = tile[half * 32 + j][d];
  __bf16* dst = ktb + ((size_t)g * DH + d) * T_SEQ + t0 + half * 32;
#pragma unroll
  for (int q4 = 0; q4 < 4; ++q4) *(bf16x8*)(dst + q4 * 8) = *(bf16x8*)(&outv[q4 * 8]);
}

// ---------------- U_c[h]: Ut[d2][d1] = sum_j gamma^(64-j) v[cC+j][d2] k[cC+j][d1] (f32) ------
// Pure-register MFMA, no LDS. grid = NH*NCHUNK, A-frags from vtb (gamma-weighted), B from ktb.
__global__ __launch_bounds__(256) void u_kernel(const __bf16* __restrict__ vtb,
                                                const __bf16* __restrict__ ktb,
                                                float* __restrict__ Ut) {
  int h = blockIdx.x >> 5, c = blockIdx.x & 31, g = h >> 2;
  int tid = threadIdx.x;
  int w = tid >> 6, l = tid & 63, lr = l & 15, lg = l >> 4;
  float l2g = log2f(1.0f - exp2f(-5.0f - (float)h));
  float ginv = exp2f(-l2g);   // 1/gamma
  f32x4 acc[2][8] = {};
#pragma unroll
  for (int kk = 0; kk < 2; ++kk) {
    int j0 = kk * 32 + lg * 8;
    float w0 = exp2f(l2g * (float)(64 - j0));
    bf16x8 aw[2];
#pragma unroll
    for (int i = 0; i < 2; ++i) {
      bf16x8 av = *(const bf16x8*)(vtb + ((size_t)g * DH + w * 32 + i * 16 + lr) * T_SEQ
                                   + c * 64 + j0);
      float wj = w0;
#pragma unroll
      for (int jj = 0; jj < 8; ++jj) { aw[i][jj] = (__bf16)((float)av[jj] * wj); wj *= ginv; }
    }
#pragma unroll
    for (int jf = 0; jf < 8; ++jf) {
      bf16x8 bv = *(const bf16x8*)(ktb + ((size_t)g * DH + jf * 16 + lr) * T_SEQ
                                   + c * 64 + j0);
      acc[0][jf] = __builtin_amdgcn_mfma_f32_16x16x32_bf16(aw[0], bv, acc[0][jf], 0, 0, 0);
      acc[1][jf] = __builtin_amdgcn_mfma_f32_16x16x32_bf16(aw[1], bv, acc[1][jf], 0, 0, 0);
    }
  }
  float* outb = Ut + (size_t)blockIdx.x * 16384;
#pragma unroll
  for (int i = 0; i < 2; ++i)
#pragma unroll
    for (int jf = 0; jf < 8; ++jf)
#pragma unroll
      for (int r = 0; r < 4; ++r)
        outb[(w * 32 + i * 16 + lg * 4 + r) * 128 + jf * 16 + lr] = acc[i][jf][r];
}

// ---------------- scan: S_{c+1} = gamma^64 S_c + U_c ; write St bf16 per chunk --------------
// grid = NH*16: h=bid>>4, row-chunk=((bid>>1)&7)*16, col-half=(bid&1)*64. 4 f32/thread.
__global__ __launch_bounds__(256) void scan_kernel(const float* __restrict__ Ut,
                                                   __bf16* __restrict__ St) {
  int bid = blockIdx.x, tid = threadIdx.x;
  int h = bid >> 4;
  int row = ((bid >> 1) & 7) * 16 + (tid >> 4);
  int col = (bid & 1) * 64 + (tid & 15) * 4;
  float l2g = log2f(1.0f - exp2f(-5.0f - (float)h));
  float df = exp2f(l2g * 64.0f);   // gamma^64
  f32x4 s = {0.f, 0.f, 0.f, 0.f};
  for (int c = 0; c < NCHUNK; ++c) {
    size_t base = ((size_t)(h * NCHUNK + c) * 128 + row) * 128 + col;
    bf16x4 o;
#pragma unroll
    for (int j = 0; j < 4; ++j) o[j] = (__bf16)s[j];
    *(bf16x4*)(St + base) = o;
    f32x4 u = *(const f32x4*)(Ut + base);
#pragma unroll
    for (int j = 0; j < 4; ++j) s[j] = df * s[j] + u[j];
  }
}

// ---------------- stage-3 attention: y = intra(diagonal tile) + gamma^(t-cC)*scale*q@S_c ----
__global__ __launch_bounds__(256) void attn2_kernel(const __bf16* __restrict__ qb,
    const __bf16* __restrict__ kb, const __bf16* __restrict__ vtb,
    const __bf16* __restrict__ St, float* __restrict__ y) {
  __shared__ __bf16 kl[64 * 128];       // [s][d], XOR-swizzled
  __shared__ __bf16 vl[128 * 64];       // [d][s], XOR-swizzled
  __shared__ __bf16 pl[4][16 * 64];     // per-wave P [t][s], XOR-swizzled
  int h = blockIdx.x >> 5, qt = blockIdx.x & 31;
  int g = h >> 2;
  int w = threadIdx.x >> 6, l = threadIdx.x & 63;
  int lr = l & 15, lg = l >> 4;
  int t0b = qt * 64;                     // chunk start cC
  int t0 = t0b + w * 16;
  bf16x8 qf[4];
#pragma unroll
  for (int kbk = 0; kbk < 4; ++kbk)
    qf[kbk] = *(const bf16x8*)(qb + ((size_t)h * T_SEQ + t0 + lr) * DH + kbk * 32 + lg * 8);
  float gamma = 1.0f - exp2f(-5.0f - (float)h);
  float l2g = log2f(gamma);
  const float scale = 0.088388347648318447f;  // 1/sqrt(128)
  // ---- stage K/V of the diagonal tile ----
  int s0 = t0b;
#pragma unroll
  for (int it = 0; it < 4; ++it) {
    int fg = it * 256 + threadIdx.x;
    {
      int ss = fg >> 4, gr = fg & 15;
      bf16x8 kv = *(const bf16x8*)(kb + ((size_t)g * T_SEQ + s0 + ss) * DH + gr * 8);
      *(bf16x8*)((char*)kl + ss * 256 + ((gr * 16) ^ ((ss & 7) << 4))) = kv;
    }
    {
      int d = fg >> 3, gv = fg & 7;
      bf16x8 vv = *(const bf16x8*)(vtb + ((size_t)g * DH + d) * T_SEQ + s0 + gv * 8);
      *(bf16x8*)((char*)vl + d * 128 + ((gv * 16) ^ ((d & 7) << 4))) = vv;
    }
  }
  // ---- inter-chunk: acc = (scale * gamma^(t-cC) * q) @ S_c  (overlaps staging drain) ----
  float wfac = scale * exp2f(l2g * (float)(w * 16 + lr));
  bf16x8 qwf[4];
#pragma unroll
  for (int kbk = 0; kbk < 4; ++kbk)
#pragma unroll
    for (int e = 0; e < 8; ++e) qwf[kbk][e] = (__bf16)((float)qf[kbk][e] * wfac);
  f32x4 acc[8] = {};
  const __bf16* Sb = St + (size_t)(h * NCHUNK + qt) * 16384;
#pragma unroll
  for (int dc = 0; dc < 8; ++dc)
#pragma unroll
    for (int kc = 0; kc < 4; ++kc) {
      bf16x8 sf = *(const bf16x8*)(Sb + (dc * 16 + lr) * 128 + kc * 32 + lg * 8);
      acc[dc] = __builtin_amdgcn_mfma_f32_16x16x32_bf16(qwf[kc], sf, acc[dc], 0, 0, 0);
    }
  __syncthreads();
  // ---- intra: QK^T -> scale*gamma^diff (causal) -> P(bf16) -> PV ----
#pragma unroll
  for (int sc = 0; sc < 4; ++sc) {
    f32x4 p = {0.f, 0.f, 0.f, 0.f};
    int srow = sc * 16 + lr;
#pragma unroll
    for (int kbk = 0; kbk < 4; ++kbk) {
      bf16x8 kf = *(const bf16x8*)((char*)kl + srow * 256 +
                                   ((kbk * 64 + lg * 16) ^ ((srow & 7) << 4)));
      p = __builtin_amdgcn_mfma_f32_16x16x32_bf16(qf[kbk], kf, p, 0, 0, 0);
    }
#pragma unroll
    for (int r = 0; r < 4; ++r) {
      int tl = lg * 4 + r;
      int diff = (w * 16 + tl) - srow;
      float val = 0.0f;
      if (diff >= 0) val = p[r] * scale * exp2f((float)diff * l2g);
      *(__bf16*)((char*)(pl[w]) + tl * 128 +
                 (((sc * 16 + lr) * 2) ^ ((tl & 7) << 4))) = (__bf16)val;
    }
  }
  bf16x8 pa[2];
#pragma unroll
  for (int kc = 0; kc < 2; ++kc)
    pa[kc] = *(const bf16x8*)((char*)(pl[w]) + lr * 128 +
                              ((kc * 64 + lg * 16) ^ ((lr & 7) << 4)));
#pragma unroll
  for (int dc = 0; dc < 8; ++dc) {
#pragma unroll
    for (int kc = 0; kc < 2; ++kc) {
      int vrow = dc * 16 + lr;
      bf16x8 vf = *(const bf16x8*)((char*)vl + vrow * 128 +
                                   ((kc * 64 + lg * 16) ^ ((vrow & 7) << 4)));
      acc[dc] = __builtin_amdgcn_mfma_f32_16x16x32_bf16(pa[kc], vf, acc[dc], 0, 0, 0);
    }
  }
#pragma unroll
  for (int dc = 0; dc < 8; ++dc)
#pragma unroll
    for (int r = 0; r < 4; ++r)
      y[((size_t)h * T_SEQ + t0 + lg * 4 + r) * DH + dc * 16 + lr] = acc[dc][r];
}

// ---------------- GEMM: 64x128 tile, BK=64, global_load_lds + XOR swizzle ----------------
template<int MODE>
__global__ __launch_bounds__(256) void gemm_gl_kernel(
    const __bf16* __restrict__ A, const __bf16* __restrict__ Bt,
    float* __restrict__ Cf, __bf16* __restrict__ Cg, int M, int N, int K) {
  __shared__ __bf16 Asb[64 * 64];
  __shared__ __bf16 Bsb[128 * 64];
  int m0 = blockIdx.x * 64, n0 = blockIdx.y * 128;
  int tid = threadIdx.x;
  int w = tid >> 6, l = tid & 63;
  int wr = w >> 1, wc = w & 1;
  int lr = l & 15, lg = l >> 4;
  int nk = K >> 6;
  const __bf16* Ab = A + (size_t)m0 * K;
  const __bf16* Bb = Bt + (size_t)n0 * K;
  f32x4 acc[2][4] = {};
  for (int kt = 0; kt < nk; ++kt) {
    int k0 = kt << 6;
#pragma unroll
    for (int c = 0; c < 2; ++c) {
      int ca = c * 256 + tid;
      int row = ca >> 3, kseg = ca & 7;
      gl_lds16(Ab + (size_t)row * K + k0 + ((kseg ^ (row & 7)) << 3), Asb + ca * 8);
    }
#pragma unroll
    for (int c = 0; c < 4; ++c) {
      int cb = c * 256 + tid;
      int row = cb >> 3, kseg = cb & 7;
      gl_lds16(Bb + (size_t)row * K + k0 + ((kseg ^ (row & 7)) << 3), Bsb + cb * 8);
    }
    __syncthreads();
    bf16x8 av[2][2], bv[4][2];
#pragma unroll
    for (int i = 0; i < 2; ++i)
#pragma unroll
      for (int kk = 0; kk < 2; ++kk) {
        int row = wr * 32 + i * 16 + lr;
        av[i][kk] = *(const bf16x8*)((const char*)Asb +
            ((row * 128 + kk * 64 + lg * 16) ^ ((lr & 7) << 4)));
      }
#pragma unroll
    for (int j = 0; j < 4; ++j)
#pragma unroll
      for (int kk = 0; kk < 2; ++kk) {
        int row = wc * 64 + j * 16 + lr;
        bv[j][kk] = *(const bf16x8*)((const char*)Bsb +
            ((row * 128 + kk * 64 + lg * 16) ^ ((lr & 7) << 4)));
      }
#pragma unroll
    for (int kk = 0; kk < 2; ++kk)
#pragma unroll
      for (int i = 0; i < 2; ++i)
#pragma unroll
        for (int j = 0; j < 4; ++j)
          acc[i][j] = __builtin_amdgcn_mfma_f32_16x16x32_bf16(av[i][kk], bv[j][kk],
                                                              acc[i][j], 0, 0, 0);
    __syncthreads();
  }
#pragma unroll
  for (int i = 0; i < 2; ++i) {
    int row = m0 + wr * 32 + i * 16 + lg * 4;
#pragma unroll
    for (int j = 0; j < 4; ++j) {
      int col = n0 + wc * 64 + j * 16 + lr;
#pragma unroll
      for (int r = 0; r < 4; ++r) {
        float z = acc[i][j][r];
        if (MODE == 0) {
          Cf[(size_t)(row + r) * N + col] = z;
        } else {
          if (n0 < 3072) {
            Cf[(size_t)(row + r) * 3072 + col] = z;
          } else {
            float sv = z / (1.0f + expf(-z));
            Cg[(size_t)(row + r) * 2048 + (col - 3072)] = (__bf16)sv;
          }
        }
      }
    }
  }
}

// ---------------- RMS norm over D per (h,t) + gate multiply -> bf16 [T][C] ----------------
__global__ __launch_bounds__(256) void rms_gate_kernel(const float* __restrict__ y,
                                                       const __bf16* __restrict__ gateb,
                                                       __bf16* __restrict__ ynormb) {
  int f = blockIdx.x * 4 + (threadIdx.x >> 6);   // row = h*2048 + t
  int l = threadIdx.x & 63;
  int h = f >> 11, t = f & 2047;
  const float* row = y + (size_t)f * DH;
  f32x2 v = *(const f32x2*)(row + 2 * l);
  float ss = v[0] * v[0] + v[1] * v[1];
#pragma unroll
  for (int o = 32; o > 0; o >>= 1) ss += __shfl_xor(ss, o, 64);
  float r = rsqrtf(ss * (1.0f / 128.0f) + 1e-5f);
  size_t base = (size_t)t * CDIM + h * DH + 2 * l;
  bf16x2 gv = *(const bf16x2*)(gateb + base);
  bf16x2 o;
  o[0] = (__bf16)(v[0] * r * (float)gv[0]);
  o[1] = (__bf16)(v[1] * r * (float)gv[1]);
  *(bf16x2*)(ynormb + base) = o;
}

extern "C" void kernel_launch(void* const* d_in, const int* in_sizes, int n_in,
                              void* d_out, int out_size, void* d_ws, size_t ws_size,
                              hipStream_t stream) {
  const float* x    = (const float*)d_in[0];
  const float* cosb = (const float*)d_in[1];
  const float* sinb = (const float*)d_in[2];
  // d_in[3] = mask (268MB) -- computed analytically, never read
  const float* Wr   = (const float*)d_in[4];
  const float* Wg   = (const float*)d_in[5];
  const float* Wp   = (const float*)d_in[6];

  char* ws = (char*)d_ws;
  size_t off = 0;
  auto alloc = [&](size_t bytes) { void* p = ws + off; off += (bytes + 255) & ~(size_t)255; return p; };
  __bf16* xb     = (__bf16*)alloc((size_t)CDIM * CDIM * 2);          // 8MB
  __bf16* wtb    = (__bf16*)alloc((size_t)5120 * CDIM * 2);          // 20MB (W_reten^T|W_gate^T)
  __bf16* wpb    = (__bf16*)alloc((size_t)CDIM * CDIM * 2);          // 8MB
  char*   qkvblk = (char*)  alloc((size_t)T_SEQ * 3072 * 4);         // 24MB (reused by y+ynorm)
  __bf16* qb     = (__bf16*)alloc((size_t)NH * T_SEQ * DH * 2);      // 8MB
  __bf16* kbp    = (__bf16*)alloc((size_t)NG * T_SEQ * DH * 2);      // 2MB
  __bf16* vtb    = (__bf16*)alloc((size_t)NG * DH * T_SEQ * 2);      // 2MB
  __bf16* ktb    = (__bf16*)alloc((size_t)NG * DH * T_SEQ * 2);      // 2MB
  __bf16* gateb  = (__bf16*)alloc((size_t)CDIM * CDIM * 2);          // 8MB
  float*  Ut     = (float*) alloc((size_t)NH * NCHUNK * 128 * 128 * 4); // 32MB
  __bf16* Stb    = (__bf16*)alloc((size_t)NH * NCHUNK * 128 * 128 * 2); // 16MB
  float*  qkv    = (float*)qkvblk;
  float*  yb     = (float*)qkvblk;                                    // alias (qkv dead by then)
  __bf16* ynormb = (__bf16*)(qkvblk + (size_t)16 * 1024 * 1024);      // alias tail of qkv block

  // 1) preprocess: cast x + transpose/cast all weights (one launch)
  pre_kernel<<<5632, 256, 0, stream>>>(x, Wr, Wg, Wp, xb, wtb, wpb);
  // 2+3) fused: [qkv | silu(gate)] = x @ [W_reten | W_gate]
  gemm_gl_kernel<1><<<dim3(32, 40), 256, 0, stream>>>(xb, wtb, qkv, gateb, 2048, 5120, 2048);
  // 4) RoPE q,k + v transpose (one launch)
  ropevt_kernel<<<2048 + NG * 32, 256, 0, stream>>>(qkv, cosb, sinb, qb, kbp, vtb);
  // 5) k transpose (needs post-RoPE k)
  kt_kernel<<<NG * 32, 256, 0, stream>>>(kbp, ktb);
  // 6) per-chunk decayed KV outer products (f32)
  u_kernel<<<NH * NCHUNK, 256, 0, stream>>>(vtb, ktb, Ut);
  // 7) state scan -> St bf16 [h][c][d2][d1]
  scan_kernel<<<NH * 16, 256, 0, stream>>>(Ut, Stb);
  // 8) attention: intra diagonal tile + q @ S_c
  attn2_kernel<<<NH * NCHUNK, 256, 0, stream>>>(qb, kbp, vtb, Stb, yb);
  // 9) RMS norm * silu_gate -> bf16 [T][C]
  rms_gate_kernel<<<NH * T_SEQ / 4, 256, 0, stream>>>(yb, gateb, ynormb);
  // 10) out = (g*y_norm) @ W_proj
  gemm_gl_kernel<0><<<dim3(32, 16), 256, 0, stream>>>(ynormb, wpb, (float*)d_out, nullptr,
                                                      2048, 2048, 2048);
}

// Round 7
// 171.956 us; speedup vs baseline: 13.9448x; 1.0560x over previous
//
#include <hip/hip_runtime.h>
#include <hip/hip_bf16.h>
#include <cstdint>
#include <cstddef>

typedef __bf16 bf16x8 __attribute__((ext_vector_type(8)));
typedef __bf16 bf16x4 __attribute__((ext_vector_type(4)));
typedef __bf16 bf16x2 __attribute__((ext_vector_type(2)));
typedef float  f32x4  __attribute__((ext_vector_type(4)));
typedef float  f32x2  __attribute__((ext_vector_type(2)));

#define T_SEQ 2048
#define CDIM  2048
#define NH    16
#define NG    4
#define DH    128
#define NCHUNK 32   // T / 64

__device__ __forceinline__ void gl_lds16(const __bf16* g, __bf16* l) {
  __builtin_amdgcn_global_load_lds(
      (const __attribute__((address_space(1))) void*)g,
      (__attribute__((address_space(3))) void*)l, 16, 0, 0);
}

// ---------------- fused preprocess: cast x->bf16, transpose+cast 3 weights ----------------
__global__ __launch_bounds__(256) void pre_kernel(
    const float* __restrict__ x, const float* __restrict__ Wr,
    const float* __restrict__ Wg, const float* __restrict__ Wp,
    __bf16* __restrict__ xb, __bf16* __restrict__ wtb, __bf16* __restrict__ wpb) {
  __shared__ __bf16 tile[64][68];
  int bid = blockIdx.x;
  int tid = threadIdx.x;
  if (bid < 2048) {   // cast x (4M elements)
    size_t i = ((size_t)bid * 256 + tid) * 8;
    f32x4 a = *(const f32x4*)(x + i);
    f32x4 b = *(const f32x4*)(x + i + 4);
    bf16x8 o;
#pragma unroll
    for (int j = 0; j < 4; ++j) { o[j] = (__bf16)a[j]; o[4 + j] = (__bf16)b[j]; }
    *(bf16x8*)(xb + i) = o;
    return;
  }
  int rel = bid - 2048;
  const float* W; __bf16* Wt; int N;
  if (rel < 1536)      { W = Wr; Wt = wtb;                        N = 3072; }
  else if (rel < 2560) { W = Wg; Wt = wtb + (size_t)3072 * CDIM;  N = 2048; rel -= 1536; }
  else                 { W = Wp; Wt = wpb;                        N = 2048; rel -= 2560; }
  const int K = 2048;
  int k0 = (rel & 31) * 64, n0 = (rel >> 5) * 64;
  int c4 = (tid & 15) * 4, r = tid >> 4;
#pragma unroll
  for (int rr = 0; rr < 4; ++rr) {
    int row = r + rr * 16;
    f32x4 v = *(const f32x4*)(W + (size_t)(k0 + row) * N + n0 + c4);
#pragma unroll
    for (int j = 0; j < 4; ++j) tile[row][c4 + j] = (__bf16)v[j];
  }
  __syncthreads();
  int n = tid >> 2, seg = tid & 3;
  __bf16 vals[16];
#pragma unroll
  for (int j = 0; j < 16; ++j) vals[j] = tile[seg * 16 + j][n];
  __bf16* dst = Wt + (size_t)(n0 + n) * K + k0 + seg * 16;
  *(bf16x8*)(dst)     = *(bf16x8*)(&vals[0]);
  *(bf16x8*)(dst + 8) = *(bf16x8*)(&vals[8]);
}

// ---- fused: RoPE q,k scatter (0..2047) | v transpose (2048..2175) | k-rope-transpose (2176..2303)
__global__ __launch_bounds__(256) void ropekt_kernel(const float* __restrict__ qkv,
    const float* __restrict__ cosb, const float* __restrict__ sinb,
    __bf16* __restrict__ qb, __bf16* __restrict__ kb,
    __bf16* __restrict__ vtb, __bf16* __restrict__ ktb) {
  __shared__ __bf16 vt[64][136];
  int bid = blockIdx.x;
  int tid = threadIdx.x;
  if (bid < 2048) {     // RoPE scatter q,k -> [head][t][d]
    int t = bid;
    int w = tid >> 6, l = tid & 63;
    float c = cosb[t * 64 + l], s = sinb[t * 64 + l];
#pragma unroll
    for (int it = 0; it < 5; ++it) {
      int slot = w + it * 4;
      int g = slot / 5, j = slot % 5;
      const float* src = qkv + (size_t)t * 3072 + g * 768 + j * 128;
      f32x2 xv = *(const f32x2*)(src + 2 * l);
      bf16x2 o;
      o[0] = (__bf16)(xv[0] * c - xv[1] * s);
      o[1] = (__bf16)(xv[0] * s + xv[1] * c);
      __bf16* dst = (j < 4) ? (qb + ((size_t)(g * 4 + j) * T_SEQ + t) * DH)
                            : (kb + ((size_t)g * T_SEQ + t) * DH);
      *(bf16x2*)(dst + 2 * l) = o;
    }
    return;
  }
  if (bid < 2176) {     // v transpose: qkv v-section [t][d] f32 -> vtb[g][d][t] bf16
    int rel = bid - 2048;
    int g = rel >> 5, t0 = (rel & 31) * 64;
#pragma unroll
    for (int it = 0; it < 8; ++it) {
      int q = it * 256 + tid;
      int tt = q >> 5, dq = q & 31;
      f32x4 v = *(const f32x4*)(qkv + (size_t)(t0 + tt) * 3072 + g * 768 + 640 + dq * 4);
#pragma unroll
      for (int j = 0; j < 4; ++j) vt[tt][dq * 4 + j] = (__bf16)v[j];
    }
    __syncthreads();
    int d = tid >> 1, half = tid & 1;
    __bf16 outv[32];
#pragma unroll
    for (int j = 0; j < 32; ++j) outv[j] = vt[half * 32 + j][d];
    __bf16* dst = vtb + ((size_t)g * DH + d) * T_SEQ + t0 + half * 32;
#pragma unroll
    for (int q4 = 0; q4 < 4; ++q4) *(bf16x8*)(dst + q4 * 8) = *(bf16x8*)(&outv[q4 * 8]);
    return;
  }
  // k-rope-transpose: qkv k-section [t][d] f32 --RoPE--> ktb[g][d][t] bf16
  int rel = bid - 2176;
  int g = rel >> 5, t0 = (rel & 31) * 64;
#pragma unroll
  for (int it = 0; it < 8; ++it) {
    int q = it * 256 + tid;
    int tt = q >> 5, dq = q & 31;           // d-offset dq*4: pairs (2*dq*2), (2*dq*2+1)
    int t = t0 + tt;
    f32x4 v = *(const f32x4*)(qkv + (size_t)t * 3072 + g * 768 + 512 + dq * 4);
    float c0 = cosb[t * 64 + dq * 2],     s0 = sinb[t * 64 + dq * 2];
    float c1 = cosb[t * 64 + dq * 2 + 1], s1 = sinb[t * 64 + dq * 2 + 1];
    vt[tt][dq * 4 + 0] = (__bf16)(v[0] * c0 - v[1] * s0);
    vt[tt][dq * 4 + 1] = (__bf16)(v[0] * s0 + v[1] * c0);
    vt[tt][dq * 4 + 2] = (__bf16)(v[2] * c1 - v[3] * s1);
    vt[tt][dq * 4 + 3] = (__bf16)(v[2] * s1 + v[3] * c1);
  }
  __syncthreads();
  int d = tid >> 1, half = tid & 1;
  __bf16 outv[32];
#pragma unroll
  for (int j = 0; j < 32; ++j) outv[j] = vt[half * 32 + j][d];
  __bf16* dst = ktb + ((size_t)g * DH + d) * T_SEQ + t0 + half * 32;
#pragma unroll
  for (int q4 = 0; q4 < 4; ++q4) *(bf16x8*)(dst + q4 * 8) = *(bf16x8*)(&outv[q4 * 8]);
}

// ---------------- fused U+scan: per (h, d2-slice, d1-half) block, sequential over chunks ----
// S_{c+1} = gamma^64 S_c + sum_j gamma^(64-j) v[cC+j][d2] k[cC+j][d1];  St[h][c] = S_c (bf16)
__global__ __launch_bounds__(256) void uscan_kernel(const __bf16* __restrict__ vtb,
                                                    const __bf16* __restrict__ ktb,
                                                    __bf16* __restrict__ St) {
  int bid = blockIdx.x;                 // NH*8*2 = 256
  int h = bid >> 4, m = (bid >> 1) & 7, half = bid & 1;
  int g = h >> 2;
  int tid = threadIdx.x, w = tid >> 6, l = tid & 63, lr = l & 15, lg = l >> 4;
  int jf = half * 4 + w;                // d1 block 0..7
  float l2g = log2f(1.0f - exp2f(-5.0f - (float)h));
  float ginv = exp2f(-l2g);             // 1/gamma
  float df   = exp2f(l2g * 64.0f);      // gamma^64
  float wk[2];
#pragma unroll
  for (int kk = 0; kk < 2; ++kk) wk[kk] = exp2f(l2g * (float)(64 - (kk * 32 + lg * 8)));
  const __bf16* vrow = vtb + ((size_t)g * DH + m * 16 + lr) * T_SEQ;
  const __bf16* krow = ktb + ((size_t)g * DH + jf * 16 + lr) * T_SEQ;
  f32x4 S = {0.f, 0.f, 0.f, 0.f};
  for (int c = 0; c < NCHUNK; ++c) {
    f32x4 u = {0.f, 0.f, 0.f, 0.f};
#pragma unroll
    for (int kk = 0; kk < 2; ++kk) {
      int j0 = c * 64 + kk * 32 + lg * 8;
      bf16x8 av = *(const bf16x8*)(vrow + j0);
      bf16x8 bv = *(const bf16x8*)(krow + j0);
      bf16x8 aw;
      float wj = wk[kk];
#pragma unroll
      for (int jj = 0; jj < 8; ++jj) { aw[jj] = (__bf16)((float)av[jj] * wj); wj *= ginv; }
      u = __builtin_amdgcn_mfma_f32_16x16x32_bf16(aw, bv, u, 0, 0, 0);
    }
    // write St[c] = S (state BEFORE chunk c), then update
    __bf16* out = St + ((size_t)(h * NCHUNK + c) * 128 + m * 16 + lg * 4) * 128 + jf * 16 + lr;
#pragma unroll
    for (int r = 0; r < 4; ++r) out[r * 128] = (__bf16)S[r];
#pragma unroll
    for (int r = 0; r < 4; ++r) S[r] = df * S[r] + u[r];
  }
}

// ---- stage-3 attention + fused RMS-norm + gate:
//   acc = intra(diagonal tile) + gamma^(t-cC)*scale*q@S_c ;
//   ynorm[t][h*128+d] = acc * rsqrt(mean_d acc^2 + eps) * gate  (bf16)
__global__ __launch_bounds__(256) void attn2_kernel(const __bf16* __restrict__ qb,
    const __bf16* __restrict__ kb, const __bf16* __restrict__ vtb,
    const __bf16* __restrict__ St, const __bf16* __restrict__ gateb,
    __bf16* __restrict__ ynormb) {
  __shared__ __bf16 kl[64 * 128];       // [s][d], XOR-swizzled
  __shared__ __bf16 vl[128 * 64];       // [d][s], XOR-swizzled
  __shared__ __bf16 pl[4][16 * 64];     // per-wave P [t][s], XOR-swizzled
  int h = blockIdx.x >> 5, qt = blockIdx.x & 31;
  int g = h >> 2;
  int w = threadIdx.x >> 6, l = threadIdx.x & 63;
  int lr = l & 15, lg = l >> 4;
  int t0b = qt * 64;                     // chunk start cC
  int t0 = t0b + w * 16;
  bf16x8 qf[4];
#pragma unroll
  for (int kbk = 0; kbk < 4; ++kbk)
    qf[kbk] = *(const bf16x8*)(qb + ((size_t)h * T_SEQ + t0 + lr) * DH + kbk * 32 + lg * 8);
  float gamma = 1.0f - exp2f(-5.0f - (float)h);
  float l2g = log2f(gamma);
  const float scale = 0.088388347648318447f;  // 1/sqrt(128)
  // ---- stage K/V of the diagonal tile ----
  int s0 = t0b;
#pragma unroll
  for (int it = 0; it < 4; ++it) {
    int fg = it * 256 + threadIdx.x;
    {
      int ss = fg >> 4, gr = fg & 15;
      bf16x8 kv = *(const bf16x8*)(kb + ((size_t)g * T_SEQ + s0 + ss) * DH + gr * 8);
      *(bf16x8*)((char*)kl + ss * 256 + ((gr * 16) ^ ((ss & 7) << 4))) = kv;
    }
    {
      int d = fg >> 3, gv = fg & 7;
      bf16x8 vv = *(const bf16x8*)(vtb + ((size_t)g * DH + d) * T_SEQ + s0 + gv * 8);
      *(bf16x8*)((char*)vl + d * 128 + ((gv * 16) ^ ((d & 7) << 4))) = vv;
    }
  }
  // ---- inter-chunk: acc = (scale * gamma^(t-cC) * q) @ S_c  (overlaps staging drain) ----
  float wfac = scale * exp2f(l2g * (float)(w * 16 + lr));
  bf16x8 qwf[4];
#pragma unroll
  for (int kbk = 0; kbk < 4; ++kbk)
#pragma unroll
    for (int e = 0; e < 8; ++e) qwf[kbk][e] = (__bf16)((float)qf[kbk][e] * wfac);
  f32x4 acc[8] = {};
  const __bf16* Sb = St + (size_t)(h * NCHUNK + qt) * 16384;
#pragma unroll
  for (int dc = 0; dc < 8; ++dc)
#pragma unroll
    for (int kc = 0; kc < 4; ++kc) {
      bf16x8 sf = *(const bf16x8*)(Sb + (dc * 16 + lr) * 128 + kc * 32 + lg * 8);
      acc[dc] = __builtin_amdgcn_mfma_f32_16x16x32_bf16(qwf[kc], sf, acc[dc], 0, 0, 0);
    }
  __syncthreads();
  // ---- intra: QK^T -> scale*gamma^diff (causal) -> P(bf16) -> PV ----
#pragma unroll
  for (int sc = 0; sc < 4; ++sc) {
    f32x4 p = {0.f, 0.f, 0.f, 0.f};
    int srow = sc * 16 + lr;
#pragma unroll
    for (int kbk = 0; kbk < 4; ++kbk) {
      bf16x8 kf = *(const bf16x8*)((char*)kl + srow * 256 +
                                   ((kbk * 64 + lg * 16) ^ ((srow & 7) << 4)));
      p = __builtin_amdgcn_mfma_f32_16x16x32_bf16(qf[kbk], kf, p, 0, 0, 0);
    }
#pragma unroll
    for (int r = 0; r < 4; ++r) {
      int tl = lg * 4 + r;
      int diff = (w * 16 + tl) - srow;
      float val = 0.0f;
      if (diff >= 0) val = p[r] * scale * exp2f((float)diff * l2g);
      *(__bf16*)((char*)(pl[w]) + tl * 128 +
                 (((sc * 16 + lr) * 2) ^ ((tl & 7) << 4))) = (__bf16)val;
    }
  }
  bf16x8 pa[2];
#pragma unroll
  for (int kc = 0; kc < 2; ++kc)
    pa[kc] = *(const bf16x8*)((char*)(pl[w]) + lr * 128 +
                              ((kc * 64 + lg * 16) ^ ((lr & 7) << 4)));
#pragma unroll
  for (int dc = 0; dc < 8; ++dc) {
#pragma unroll
    for (int kc = 0; kc < 2; ++kc) {
      int vrow = dc * 16 + lr;
      bf16x8 vf = *(const bf16x8*)((char*)vl + vrow * 128 +
                                   ((kc * 64 + lg * 16) ^ ((vrow & 7) << 4)));
      acc[dc] = __builtin_amdgcn_mfma_f32_16x16x32_bf16(pa[kc], vf, acc[dc], 0, 0, 0);
    }
  }
  // ---- fused RMS over d (16 lr-lanes x 8 dc) per row (lg, r) + gate + bf16 store ----
  float rs[4];
#pragma unroll
  for (int r = 0; r < 4; ++r) {
    float ssum = 0.f;
#pragma unroll
    for (int dc = 0; dc < 8; ++dc) ssum += acc[dc][r] * acc[dc][r];
    ssum += __shfl_xor(ssum, 1, 64);
    ssum += __shfl_xor(ssum, 2, 64);
    ssum += __shfl_xor(ssum, 4, 64);
    ssum += __shfl_xor(ssum, 8, 64);
    rs[r] = rsqrtf(ssum * (1.0f / 128.0f) + 1e-5f);
  }
#pragma unroll
  for (int dc = 0; dc < 8; ++dc)
#pragma unroll
    for (int r = 0; r < 4; ++r) {
      size_t idx = (size_t)(t0 + lg * 4 + r) * CDIM + h * DH + dc * 16 + lr;
      float gv = (float)gateb[idx];
      ynormb[idx] = (__bf16)(acc[dc][r] * rs[r] * gv);
    }
}

// ---------------- GEMM: 64x128 tile, BK=64, global_load_lds + XOR swizzle ----------------
template<int MODE>
__global__ __launch_bounds__(256) void gemm_gl_kernel(
    const __bf16* __restrict__ A, const __bf16* __restrict__ Bt,
    float* __restrict__ Cf, __bf16* __restrict__ Cg, int M, int N, int K) {
  __shared__ __bf16 Asb[64 * 64];
  __shared__ __bf16 Bsb[128 * 64];
  int m0 = blockIdx.x * 64, n0 = blockIdx.y * 128;
  int tid = threadIdx.x;
  int w = tid >> 6, l = tid & 63;
  int wr = w >> 1, wc = w & 1;
  int lr = l & 15, lg = l >> 4;
  int nk = K >> 6;
  const __bf16* Ab = A + (size_t)m0 * K;
  const __bf16* Bb = Bt + (size_t)n0 * K;
  f32x4 acc[2][4] = {};
  for (int kt = 0; kt < nk; ++kt) {
    int k0 = kt << 6;
#pragma unroll
    for (int c = 0; c < 2; ++c) {
      int ca = c * 256 + tid;
      int row = ca >> 3, kseg = ca & 7;
      gl_lds16(Ab + (size_t)row * K + k0 + ((kseg ^ (row & 7)) << 3), Asb + ca * 8);
    }
#pragma unroll
    for (int c = 0; c < 4; ++c) {
      int cb = c * 256 + tid;
      int row = cb >> 3, kseg = cb & 7;
      gl_lds16(Bb + (size_t)row * K + k0 + ((kseg ^ (row & 7)) << 3), Bsb + cb * 8);
    }
    __syncthreads();
    bf16x8 av[2][2], bv[4][2];
#pragma unroll
    for (int i = 0; i < 2; ++i)
#pragma unroll
      for (int kk = 0; kk < 2; ++kk) {
        int row = wr * 32 + i * 16 + lr;
        av[i][kk] = *(const bf16x8*)((const char*)Asb +
            ((row * 128 + kk * 64 + lg * 16) ^ ((lr & 7) << 4)));
      }
#pragma unroll
    for (int j = 0; j < 4; ++j)
#pragma unroll
      for (int kk = 0; kk < 2; ++kk) {
        int row = wc * 64 + j * 16 + lr;
        bv[j][kk] = *(const bf16x8*)((const char*)Bsb +
            ((row * 128 + kk * 64 + lg * 16) ^ ((lr & 7) << 4)));
      }
#pragma unroll
    for (int kk = 0; kk < 2; ++kk)
#pragma unroll
      for (int i = 0; i < 2; ++i)
#pragma unroll
        for (int j = 0; j < 4; ++j)
          acc[i][j] = __builtin_amdgcn_mfma_f32_16x16x32_bf16(av[i][kk], bv[j][kk],
                                                              acc[i][j], 0, 0, 0);
    __syncthreads();
  }
#pragma unroll
  for (int i = 0; i < 2; ++i) {
    int row = m0 + wr * 32 + i * 16 + lg * 4;
#pragma unroll
    for (int j = 0; j < 4; ++j) {
      int col = n0 + wc * 64 + j * 16 + lr;
#pragma unroll
      for (int r = 0; r < 4; ++r) {
        float z = acc[i][j][r];
        if (MODE == 0) {
          Cf[(size_t)(row + r) * N + col] = z;
        } else {
          if (n0 < 3072) {
            Cf[(size_t)(row + r) * 3072 + col] = z;
          } else {
            float sv = z / (1.0f + expf(-z));
            Cg[(size_t)(row + r) * 2048 + (col - 3072)] = (__bf16)sv;
          }
        }
      }
    }
  }
}

extern "C" void kernel_launch(void* const* d_in, const int* in_sizes, int n_in,
                              void* d_out, int out_size, void* d_ws, size_t ws_size,
                              hipStream_t stream) {
  const float* x    = (const float*)d_in[0];
  const float* cosb = (const float*)d_in[1];
  const float* sinb = (const float*)d_in[2];
  // d_in[3] = mask (268MB) -- computed analytically, never read
  const float* Wr   = (const float*)d_in[4];
  const float* Wg   = (const float*)d_in[5];
  const float* Wp   = (const float*)d_in[6];

  char* ws = (char*)d_ws;
  size_t off = 0;
  auto alloc = [&](size_t bytes) { void* p = ws + off; off += (bytes + 255) & ~(size_t)255; return p; };
  __bf16* xb     = (__bf16*)alloc((size_t)CDIM * CDIM * 2);          // 8MB
  __bf16* wtb    = (__bf16*)alloc((size_t)5120 * CDIM * 2);          // 20MB (W_reten^T|W_gate^T)
  __bf16* wpb    = (__bf16*)alloc((size_t)CDIM * CDIM * 2);          // 8MB
  char*   qkvblk = (char*)  alloc((size_t)T_SEQ * 3072 * 4);         // 24MB (qkv f32; later ynorm)
  __bf16* qb     = (__bf16*)alloc((size_t)NH * T_SEQ * DH * 2);      // 8MB
  __bf16* kbp    = (__bf16*)alloc((size_t)NG * T_SEQ * DH * 2);      // 2MB
  __bf16* vtb    = (__bf16*)alloc((size_t)NG * DH * T_SEQ * 2);      // 2MB
  __bf16* ktb    = (__bf16*)alloc((size_t)NG * DH * T_SEQ * 2);      // 2MB
  __bf16* gateb  = (__bf16*)alloc((size_t)CDIM * CDIM * 2);          // 8MB
  __bf16* Stb    = (__bf16*)alloc((size_t)NH * NCHUNK * 128 * 128 * 2); // 16MB
  float*  qkv    = (float*)qkvblk;
  __bf16* ynormb = (__bf16*)qkvblk;    // alias: qkv fully consumed before attn2 writes

  // 1) preprocess: cast x + transpose/cast all weights
  pre_kernel<<<5632, 256, 0, stream>>>(x, Wr, Wg, Wp, xb, wtb, wpb);
  // 2) fused: [qkv | silu(gate)] = x @ [W_reten | W_gate]
  gemm_gl_kernel<1><<<dim3(32, 40), 256, 0, stream>>>(xb, wtb, qkv, gateb, 2048, 5120, 2048);
  // 3) RoPE q,k scatter + v transpose + k-rope-transpose (one launch)
  ropekt_kernel<<<2048 + NG * 32 * 2, 256, 0, stream>>>(qkv, cosb, sinb, qb, kbp, vtb, ktb);
  // 4) fused per-chunk decayed KV outer products + state scan -> St bf16
  uscan_kernel<<<256, 256, 0, stream>>>(vtb, ktb, Stb);
  // 5) attention (intra tile + q@S_c) + fused RMS-norm + gate -> ynorm bf16 [T][C]
  attn2_kernel<<<NH * NCHUNK, 256, 0, stream>>>(qb, kbp, vtb, Stb, gateb, ynormb);
  // 6) out = (g*y_norm) @ W_proj
  gemm_gl_kernel<0><<<dim3(32, 16), 256, 0, stream>>>(ynormb, wpb, (float*)d_out, nullptr,
                                                      2048, 2048, 2048);
}